// Round 11
// baseline (105.267 us; speedup 1.0000x reference)
//
#include <hip/hip_runtime.h>

#define BATCH  4096
#define LEN    8192
#define NB     12
#define TPB    256
#define EPT    32   // elements per thread; TPB*EPT == LEN

typedef _Float16 h2v __attribute__((ext_vector_type(2)));
typedef __fp16   g2v __attribute__((ext_vector_type(2)));

__device__ __forceinline__ h2v pkrtz(float a0, float a1) {
    g2v r = __builtin_amdgcn_cvt_pkrtz(a0, a1);   // v_cvt_pkrtz_f16_f32
    return __builtin_bit_cast(h2v, r);
}

// packed shifted-elu for two pre-activations (as = a*log2e, f32 in):
// ep = max(min(2^as, 1), 1 + ln2*as), computed in f16x2.
//   as<0: 2^as<1 -> exp branch; as>=0: min->1, lin=1+a>=1 -> linear branch.
__device__ __forceinline__ h2v elu2(float a0, float a1, h2v ln2_2, h2v one2) {
    h2v as2 = pkrtz(a0, a1);
    h2v e2  = __builtin_elementwise_exp2(as2);             // 2x v_exp_f16
    e2      = __builtin_elementwise_min(e2, one2);         // v_pk_min_f16
    h2v lin = __builtin_elementwise_fma(as2, ln2_2, one2); // v_pk_fma_f16
    return __builtin_elementwise_max(e2, lin);             // v_pk_max_f16
}

__global__ __launch_bounds__(TPB, 8)
void resconv1d_kernel(const float* __restrict__ x_in,
                      const float* __restrict__ w1,
                      const float* __restrict__ b1,
                      const float* __restrict__ w2,
                      const float* __restrict__ b2,
                      float* __restrict__ out)
{
    // halo exchange buffers (double-buffered -> one barrier per block-iter)
    __shared__ float s_first[2][TPB];
    __shared__ float s_last [2][TPB];

    const int t   = threadIdx.x;
    const int row = blockIdx.x;

    // ---- load this thread's 32 contiguous elements (8x float4) ----
    const float* xp = x_in + (size_t)row * LEN + (size_t)t * EPT;
    float y[EPT];   // carried representation: y = x + D (D starts at 0)
    #pragma unroll
    for (int k = 0; k < EPT / 4; ++k) {
        float4 v = reinterpret_cast<const float4*>(xp)[k];
        y[4*k+0] = v.x; y[4*k+1] = v.y; y[4*k+2] = v.z; y[4*k+3] = v.w;
    }

    // loop-invariant halo indices / edge flags
    const int  idxl = (t > 0)       ? t - 1 : 0;
    const int  idxr = (t < TPB - 1) ? t + 1 : TPB - 1;
    const bool at_l = (t == 0);
    const bool at_r = (t == TPB - 1);

    float D = 0.0f;   // y = x + D; updated uniformly each iteration

    #pragma unroll 1
    for (int it = 0; it < NB; ++it) {
        const int buf = it & 1;
        s_first[buf][t] = y[0];
        s_last [buf][t] = y[EPT-1];
        __syncthreads();

        // ---- uniform weight loads (loop-uniform -> scalar) ----
        const float LOG2E = 1.4426950408889634f;
        const float w10s = w1[2*it]   * LOG2E;
        const float w11s = w1[2*it+1] * LOG2E;
        const float aw20 = 0.9f * w2[2*it];
        const float aw21 = 0.9f * w2[2*it+1];
        const float cc   = 0.9f * b2[it] - aw20 - aw21;
        // fold carried offset into conv1 bias:
        const float b1p  = fmaf(-D, w10s + w11s, b1[it] * LOG2E);

        const h2v w2pk  = { (_Float16)aw20, (_Float16)aw21 };
        const h2v one2  = { (_Float16)1.0f, (_Float16)1.0f };
        const h2v ln2_2 = { (_Float16)0.693147181f, (_Float16)0.693147181f };

        // halo in y-representation; row edge x==0 corresponds to y==D
        const float yl = at_l ? D : s_last [buf][idxl];
        const float yr = at_r ? D : s_first[buf][idxr];

        // prologue: pair {ep_0, ep_1}
        const float a0 = fmaf(w10s, yl,   fmaf(w11s, y[0], b1p));
        const float a1 = fmaf(w10s, y[0], fmaf(w11s, y[1], b1p));
        h2v epc = elu2(a0, a1, ln2_2, one2);

        #pragma unroll
        for (int k = 0; k < EPT; k += 2) {
            // next pair {ep_{k+2}, ep_{k+3}} (hi half dummy on the tail)
            const float an0 = (k + 2 < EPT)
                ? fmaf(w10s, y[k+1],   fmaf(w11s, y[k+2], b1p))
                : fmaf(w10s, y[EPT-1], fmaf(w11s, yr,     b1p));
            const float an1 = (k + 3 < EPT)
                ? fmaf(w10s, y[k+2], fmaf(w11s, y[k+3], b1p))
                : an0;   // dummy
            const h2v epn = elu2(an0, an1, ln2_2, one2);

            // combine (cc carried in D): y[j] += aw20*ep_j + aw21*ep_{j+1}
            // f16 products, f32 accumulate (v_dot2_f32_f16)
            y[k]   = __builtin_amdgcn_fdot2(w2pk, epc, y[k],   false);
            const h2v mix = { epc[1], epn[0] };
            y[k+1] = __builtin_amdgcn_fdot2(w2pk, mix, y[k+1], false);
            epc = epn;
        }
        D -= cc;   // uniform across all threads
        // next iteration writes the other halo buffer; one barrier/iter safe
    }

    // ---- store: undo the carried offset (x = y - D_final) ----
    float* op = out + (size_t)row * LEN + (size_t)t * EPT;
    #pragma unroll
    for (int k = 0; k < EPT / 4; ++k) {
        float4 v = make_float4(y[4*k+0] - D, y[4*k+1] - D,
                               y[4*k+2] - D, y[4*k+3] - D);
        reinterpret_cast<float4*>(op)[k] = v;
    }
}

extern "C" void kernel_launch(void* const* d_in, const int* in_sizes, int n_in,
                              void* d_out, int out_size, void* d_ws, size_t ws_size,
                              hipStream_t stream) {
    const float* x  = (const float*)d_in[0];
    const float* w1 = (const float*)d_in[1];
    const float* b1 = (const float*)d_in[2];
    const float* w2 = (const float*)d_in[3];
    const float* b2 = (const float*)d_in[4];
    float* out = (float*)d_out;

    resconv1d_kernel<<<dim3(BATCH), dim3(TPB), 0, stream>>>(x, w1, b1, w2, b2, out);
}